// Round 7
// baseline (385.980 us; speedup 1.0000x reference)
//
#include <hip/hip_runtime.h>
#include <hip/hip_bf16.h>
#include <type_traits>

typedef __bf16 bf16;
typedef __bf16 bf16x8 __attribute__((ext_vector_type(8)));
typedef float floatx4 __attribute__((ext_vector_type(4)));
typedef short short4v __attribute__((ext_vector_type(4)));

#if __has_builtin(__builtin_amdgcn_mfma_f32_16x16x16bf16_1k)
#define DIRECT_PV 1
#else
#define DIRECT_PV 0
#endif

#if __has_builtin(__builtin_amdgcn_exp2f)
#define EXP2(x) __builtin_amdgcn_exp2f(x)
#else
#define EXP2(x) exp2f(x)
#endif

#define QSCALE 0.18033688011112043f  // 0.125 * log2(e)

__device__ __forceinline__ void glds16(const bf16* g, bf16* l) {
  __builtin_amdgcn_global_load_lds((const __attribute__((address_space(1))) void*)g,
                                   (__attribute__((address_space(3))) void*)l, 16, 0, 0);
}

__device__ __forceinline__ unsigned pack_bf16(float a, float b) {
  unsigned short ua = __builtin_bit_cast(unsigned short, (bf16)a);
  unsigned short ub = __builtin_bit_cast(unsigned short, (bf16)b);
  return (unsigned)ua | ((unsigned)ub << 16);
}

// ---------------- fused preprocessing: converts, bias concat, 7 weight transposes --
struct PrepArgs {
  const float* x; const float* xc;
  bf16* xbf; bf16* xcbf;
  const float* b4[4];   // bq,bk,bv,bcq
  const float* bc[2];   // bck,bcv
  float* bias4; float* biasc;
  const float* W[7];    // Wq,Wk,Wv,Wcq,Wp,Wck,Wcv
  bf16* WT[7];
};

__global__ __launch_bounds__(256) void prep_kernel(PrepArgs a) {
  __shared__ bf16 tsh[32][33];
  const int bx = blockIdx.x, tid = threadIdx.x;
  if (bx < 4096) {  // x fp32->bf16
    int i = bx * 256 + tid;
    float4 f = ((const float4*)a.x)[i];
    bf16 t[4] = {(bf16)f.x, (bf16)f.y, (bf16)f.z, (bf16)f.w};
    *(uint2*)&a.xbf[(long)i * 4] = *(const uint2*)t;
  } else if (bx < 4608) {  // xc fp32->bf16
    int i = (bx - 4096) * 256 + tid;
    float4 f = ((const float4*)a.xc)[i];
    bf16 t[4] = {(bf16)f.x, (bf16)f.y, (bf16)f.z, (bf16)f.w};
    *(uint2*)&a.xcbf[(long)i * 4] = *(const uint2*)t;
  } else if (bx < 4632) {  // bias concat
    int lb = bx - 4608;
    if (lb < 16) { int i = lb * 256 + tid; a.bias4[i] = a.b4[i >> 10][i & 1023]; }
    else         { int i = (lb - 16) * 256 + tid; a.biasc[i] = a.bc[i >> 10][i & 1023]; }
  } else {  // weight transpose [R,1024] fp32 -> [1024,R] bf16
    int t = bx - 4632, w, R, bxw, byw;
    if (t < 5120) { w = t >> 10; R = 1024; int l = t & 1023; bxw = l & 31; byw = l >> 5; }
    else { int t2 = t - 5120; w = 5 + (t2 >> 9); R = 512; int l = t2 & 511; bxw = l & 31; byw = l >> 5; }
    const float* in = a.W[w];
    bf16* out = a.WT[w];
    int tx = tid & 31, ty = tid >> 5;
    int c = bxw * 32 + tx;
#pragma unroll
    for (int i = 0; i < 4; i++) {
      int r = byw * 32 + ty + i * 8;
      tsh[ty + i * 8][tx] = (bf16)in[(long)r * 1024 + c];
    }
    __syncthreads();
    int oc = byw * 32 + tx;
#pragma unroll
    for (int i = 0; i < 4; i++) {
      int orr = bxw * 32 + ty + i * 8;
      out[(long)orr * R + oc] = tsh[tx][ty + i * 8];
    }
  }
}

// ---------------- 128x128 m97-style GEMM: C[M,N] = A[M,K] @ Bt[N,K]^T + bias -------
// qflag: scale Q/Qc columns (col<1024 || col>=3072) by QSCALE in the epilogue.
template <typename OutT>
__global__ __launch_bounds__(256, 3) void gemm128(const bf16* __restrict__ A,
                                                  const bf16* __restrict__ Bt,
                                                  const float* __restrict__ bias,
                                                  OutT* __restrict__ C,
                                                  int M, int N, int K, int ldc,
                                                  bf16* __restrict__ Vt,
                                                  int vcol0, int vcol1, int Lt, int tok_shift,
                                                  int qflag) {
  __shared__ alignas(16) bf16 As[128 * 32];
  __shared__ alignas(16) bf16 Bs[128 * 32];
  const int tid = threadIdx.x, wave = tid >> 6, lane = tid & 63;
  const int l16 = lane & 15, l4 = lane >> 4;
  const int wm = wave & 1, wn = wave >> 1;
  const int n0 = blockIdx.x * 128, m0 = blockIdx.y * 128;
  const int lrow = lane >> 2, lch = (lane & 3) * 8;

  floatx4 acc[4][4];
#pragma unroll
  for (int mt = 0; mt < 4; mt++)
#pragma unroll
    for (int nt = 0; nt < 4; nt++) acc[mt][nt] = (floatx4){0.f, 0.f, 0.f, 0.f};

  const bf16* Ag = A + (long)(m0 + wave * 32 + lrow) * K + lch;
  const bf16* Bg = Bt + (long)(n0 + wave * 32 + lrow) * K + lch;
  bf16* Al = &As[(wave * 32) * 32];
  bf16* Bl = &Bs[(wave * 32) * 32];

  for (int k0 = 0; k0 < K; k0 += 32) {
    __syncthreads();
    glds16(Ag + k0, Al);
    glds16(Ag + k0 + (long)16 * K, Al + 16 * 32);
    glds16(Bg + k0, Bl);
    glds16(Bg + k0 + (long)16 * K, Bl + 16 * 32);
    __syncthreads();
    bf16x8 a[4], b[4];
#pragma unroll
    for (int mt = 0; mt < 4; mt++) a[mt] = *(const bf16x8*)&As[(wm * 64 + mt * 16 + l16) * 32 + l4 * 8];
#pragma unroll
    for (int nt = 0; nt < 4; nt++) b[nt] = *(const bf16x8*)&Bs[(wn * 64 + nt * 16 + l16) * 32 + l4 * 8];
#pragma unroll
    for (int mt = 0; mt < 4; mt++)
#pragma unroll
      for (int nt = 0; nt < 4; nt++)
        acc[mt][nt] = __builtin_amdgcn_mfma_f32_16x16x32_bf16(a[mt], b[nt], acc[mt][nt], 0, 0, 0);
  }

  const bool vpath = (vcol0 >= 0) && (n0 >= vcol0) && (n0 < vcol1);
  if (!vpath) {
    const int coladj = (vcol0 >= 0 && n0 >= vcol1) ? (vcol1 - vcol0) : 0;
#pragma unroll
    for (int nt = 0; nt < 4; nt++) {
      int col = n0 + wn * 64 + nt * 16 + l16;
      float bv = bias[col];
      float sc = (qflag && (col < 1024 || col >= 3072)) ? QSCALE : 1.0f;
#pragma unroll
      for (int mt = 0; mt < 4; mt++)
#pragma unroll
        for (int r = 0; r < 4; r++) {
          int row = m0 + wm * 64 + mt * 16 + l4 * 4 + r;
          float v = (acc[mt][nt][r] + bv) * sc;
          if constexpr (std::is_same_v<OutT, float>) C[(long)row * ldc + col - coladj] = v;
          else                                       C[(long)row * ldc + col - coladj] = (bf16)v;
        }
    }
  } else {
#pragma unroll
    for (int nt = 0; nt < 4; nt++) {
      int col = n0 + wn * 64 + nt * 16 + l16;
      int c = col - vcol0, hh = c >> 6, dd = c & 63;
      float bv = bias[col];
#pragma unroll
      for (int mt = 0; mt < 4; mt++) {
        int t0 = m0 + wm * 64 + mt * 16 + l4 * 4;
        int bb = t0 >> tok_shift, t = t0 & ((1 << tok_shift) - 1);
        bf16 tmp[4];
#pragma unroll
        for (int r = 0; r < 4; r++) tmp[r] = (bf16)(acc[mt][nt][r] + bv);
        *(uint2*)&Vt[(((long)bb * 16 + hh) * 64 + dd) * Lt + t] = *(const uint2*)tmp;
      }
    }
  }
}

// ---------------- barrier-free fused self(causal)+cross flash attention ------------
// grid (32 bh, 32 qt'): qt = 31-qt' (heavy first); bh-major => (b,h) K/V stays in one
// XCD's L2. Keys striped across waves; independent per-wave online softmax;
// flash-combine across waves once/phase. DIRECT_PV: S^T C-frag (row=key=l4*4+r,
// col=q=l16) IS the B-frag (k=l4*4+j, n=l16) of v_mfma_f32_16x16x16_bf16 -> P feeds
// PV straight from registers, zero LDS in the k-loop.
__global__ __launch_bounds__(256, 3) void attn_kernel(const bf16* __restrict__ QKQc,
                                                      const bf16* __restrict__ VtB,
                                                      const bf16* __restrict__ KcB,
                                                      const bf16* __restrict__ VctB,
                                                      bf16* __restrict__ Y) {
  __shared__ float2 Mbuf[4][4][16];           // [wave][qt][l16] = (m, l)
  __shared__ alignas(16) bf16 U[4 * 64 * 72]; // Obuf [w][64q][72d] (+ fallback P slabs)
  const int tid = threadIdx.x, w = tid >> 6, lane = tid & 63;
  const int l16 = lane & 15, l4 = lane >> 4;
  const int bh = blockIdx.x, h = bh & 15, b = bh >> 4;
  const int qt = 31 - (int)blockIdx.y;
  const int q0 = qt * 64;
  const int wk = w * 32;                      // wave's key offset inside a 128-tile
  const float NEG = -1e30f;
#if !DIRECT_PV
  bf16* Pw = U + w * (64 * 44);               // wave-private, stride 44 (conflict-min)
#endif

  float o_self[16];

  for (int phase = 0; phase < 2; phase++) {
    const bf16 *Qb, *Kb, *Vtb;
    int kstr, vtstr, nkt;
    if (phase == 0) {
      Qb = QKQc + (long)b * 2048 * 3072 + h * 64;
      Kb = Qb + 1024;                              kstr = 3072;
      Vtb = VtB + ((long)b * 16 + h) * 64 * 2048;  vtstr = 2048;
      nkt = (qt + 2) >> 1;
    } else {
      Qb = QKQc + (long)b * 2048 * 3072 + h * 64 + 2048;
      Kb = KcB + (long)b * 512 * 1024 + h * 64;    kstr = 1024;
      Vtb = VctB + ((long)b * 16 + h) * 64 * 512;  vtstr = 512;
      nkt = 4;
    }

    __syncthreads();  // U/Mbuf safe to reuse across phases

    // Q B-frags for the whole phase (scale pre-folded in GEMM epilogue)
    bf16x8 qf[4][2];
#pragma unroll
    for (int qtt = 0; qtt < 4; qtt++) {
      const bf16* qp = Qb + (long)(q0 + qtt * 16 + l16) * 3072 + l4 * 8;
#pragma unroll
      for (int ds = 0; ds < 2; ds++) qf[qtt][ds] = *(const bf16x8*)(qp + ds * 32);
    }

    float m_i[4], l_i[4];
#pragma unroll
    for (int qtt = 0; qtt < 4; qtt++) { m_i[qtt] = NEG; l_i[qtt] = 0.f; }
    floatx4 oacc[4][4];  // [mtd (d)][qt]: O^T, col=q=l16, row=d=l4*4+r
#pragma unroll
    for (int mtd = 0; mtd < 4; mtd++)
#pragma unroll
      for (int qtt = 0; qtt < 4; qtt++) oacc[mtd][qtt] = (floatx4){0.f, 0.f, 0.f, 0.f};

    // prefetch K tile 0 (wave's own 32 keys)
    bf16x8 kc[2][2], kn[2][2];
#pragma unroll
    for (int mt = 0; mt < 2; mt++)
#pragma unroll
      for (int ds = 0; ds < 2; ds++)
        kc[mt][ds] = *(const bf16x8*)(Kb + (long)(wk + mt * 16 + l16) * kstr + ds * 32 + l4 * 8);

    for (int kt = 0; kt < nkt; kt++) {
      const int kbase = kt * 128 + wk;
      // V^T fragments for this tile (consumed at iteration end -> latency hidden)
#if DIRECT_PV
      uint2 vf[4][2];  // A-frag K=16: m=d=l16, k=key=l4*4+j
#pragma unroll
      for (int mtd = 0; mtd < 4; mtd++)
#pragma unroll
        for (int mt = 0; mt < 2; mt++)
          vf[mtd][mt] = *(const uint2*)(Vtb + (long)(mtd * 16 + l16) * vtstr + kbase + mt * 16 + l4 * 4);
#else
      bf16x8 vc[4];
#pragma unroll
      for (int mtd = 0; mtd < 4; mtd++)
        vc[mtd] = *(const bf16x8*)(Vtb + (long)(mtd * 16 + l16) * vtstr + kbase + l4 * 8);
#endif

      // S^T tiles: A = K rows (m=key), B = Q rows (n=q)
      floatx4 sacc[2][4];
#pragma unroll
      for (int mt = 0; mt < 2; mt++)
#pragma unroll
        for (int qtt = 0; qtt < 4; qtt++) sacc[mt][qtt] = (floatx4){0.f, 0.f, 0.f, 0.f};
#pragma unroll
      for (int ds = 0; ds < 2; ds++)
#pragma unroll
        for (int mt = 0; mt < 2; mt++)
#pragma unroll
          for (int qtt = 0; qtt < 4; qtt++)
            sacc[mt][qtt] = __builtin_amdgcn_mfma_f32_16x16x32_bf16(kc[mt][ds], qf[qtt][ds], sacc[mt][qtt], 0, 0, 0);

      if (kt + 1 < nkt) {  // prefetch next K
        const int nb = kbase + 128;
#pragma unroll
        for (int mt = 0; mt < 2; mt++)
#pragma unroll
          for (int ds = 0; ds < 2; ds++)
            kn[mt][ds] = *(const bf16x8*)(Kb + (long)(nb + mt * 16 + l16) * kstr + ds * 32 + l4 * 8);
      }

      // causal mask (finite NEG; only last self tile straddles)
      if (phase == 0 && kt == nkt - 1) {
#pragma unroll
        for (int mt = 0; mt < 2; mt++) {
          int keyb = kbase + mt * 16 + l4 * 4;
#pragma unroll
          for (int qtt = 0; qtt < 4; qtt++) {
            int q = q0 + qtt * 16 + l16;
#pragma unroll
            for (int r = 0; r < 4; r++)
              if (keyb + r > q) sacc[mt][qtt][r] = NEG;
          }
        }
      }

      // per-wave online softmax (reduce across l4 groups only: xor 16, 32)
      float alpha[4];
      uint2 pd[4][2];
      int changed = 0;
#pragma unroll
      for (int qtt = 0; qtt < 4; qtt++) {
        float mx = fmaxf(fmaxf(fmaxf(sacc[0][qtt][0], sacc[0][qtt][1]), fmaxf(sacc[0][qtt][2], sacc[0][qtt][3])),
                         fmaxf(fmaxf(sacc[1][qtt][0], sacc[1][qtt][1]), fmaxf(sacc[1][qtt][2], sacc[1][qtt][3])));
        mx = fmaxf(mx, __shfl_xor(mx, 16));
        mx = fmaxf(mx, __shfl_xor(mx, 32));
        mx = fmaxf(mx, m_i[qtt]);
        alpha[qtt] = EXP2(m_i[qtt] - mx);
        changed |= (mx > m_i[qtt]) ? 1 : 0;
        m_i[qtt] = mx;
        float rs = 0.f;
#pragma unroll
        for (int mt = 0; mt < 2; mt++) {
          float p0 = EXP2(sacc[mt][qtt][0] - mx), p1 = EXP2(sacc[mt][qtt][1] - mx);
          float p2 = EXP2(sacc[mt][qtt][2] - mx), p3 = EXP2(sacc[mt][qtt][3] - mx);
          rs += (p0 + p1) + (p2 + p3);
          pd[qtt][mt].x = pack_bf16(p0, p1);
          pd[qtt][mt].y = pack_bf16(p2, p3);
        }
        rs += __shfl_xor(rs, 16);
        rs += __shfl_xor(rs, 32);
        l_i[qtt] = l_i[qtt] * alpha[qtt] + rs;
      }
      if (__any(changed)) {
#pragma unroll
        for (int mtd = 0; mtd < 4; mtd++)
#pragma unroll
          for (int qtt = 0; qtt < 4; qtt++)
#pragma unroll
            for (int r = 0; r < 4; r++) oacc[mtd][qtt][r] *= alpha[qtt];
      }

#if DIRECT_PV
      // O^T += V^T · P^T : P C-frag IS the K=16 B-frag — zero data movement
#pragma unroll
      for (int qtt = 0; qtt < 4; qtt++)
#pragma unroll
        for (int mt = 0; mt < 2; mt++) {
          short4v pf = __builtin_bit_cast(short4v, pd[qtt][mt]);
#pragma unroll
          for (int mtd = 0; mtd < 4; mtd++)
            oacc[mtd][qtt] = __builtin_amdgcn_mfma_f32_16x16x16bf16_1k(
                __builtin_bit_cast(short4v, vf[mtd][mt]), pf, oacc[mtd][qtt], 0, 0, 0);
        }
#else
      // P^T round-trip through wave-private slab (stride 44 = conflict-minimal)
#pragma unroll
      for (int qtt = 0; qtt < 4; qtt++)
#pragma unroll
        for (int mt = 0; mt < 2; mt++)
          *(uint2*)&Pw[(qtt * 16 + l16) * 44 + mt * 16 + l4 * 4] = pd[qtt][mt];
#pragma unroll
      for (int qtt = 0; qtt < 4; qtt++) {
        bf16x8 pf = *(const bf16x8*)&Pw[(qtt * 16 + l16) * 44 + l4 * 8];
#pragma unroll
        for (int mtd = 0; mtd < 4; mtd++)
          oacc[mtd][qtt] = __builtin_amdgcn_mfma_f32_16x16x32_bf16(vc[mtd], pf, oacc[mtd][qtt], 0, 0, 0);
      }
#endif
#pragma unroll
      for (int mt = 0; mt < 2; mt++)
#pragma unroll
        for (int ds = 0; ds < 2; ds++) kc[mt][ds] = kn[mt][ds];
    }  // kt

    // ---- flash-combine across the 4 waves ----
    if (l4 == 0) {
#pragma unroll
      for (int qtt = 0; qtt < 4; qtt++) Mbuf[w][qtt][l16] = make_float2(m_i[qtt], l_i[qtt]);
    }
    __syncthreads();
    float myscale[4], denom[4];
#pragma unroll
    for (int qtt = 0; qtt < 4; qtt++) {
      float2 s0 = Mbuf[0][qtt][l16], s1 = Mbuf[1][qtt][l16];
      float2 s2 = Mbuf[2][qtt][l16], s3 = Mbuf[3][qtt][l16];
      float M = fmaxf(fmaxf(s0.x, s1.x), fmaxf(s2.x, s3.x));
      denom[qtt] = EXP2(s0.x - M) * s0.y + EXP2(s1.x - M) * s1.y +
                   EXP2(s2.x - M) * s2.y + EXP2(s3.x - M) * s3.y;
      myscale[qtt] = EXP2(m_i[qtt] - M);
    }
    // scaled O^T partials (bf16) -> Obuf[w][q][d]
#pragma unroll
    for (int qtt = 0; qtt < 4; qtt++)
#pragma unroll
      for (int mtd = 0; mtd < 4; mtd++) {
        float s = myscale[qtt];
        uint2 u = {pack_bf16(oacc[mtd][qtt][0] * s, oacc[mtd][qtt][1] * s),
                   pack_bf16(oacc[mtd][qtt][2] * s, oacc[mtd][qtt][3] * s)};
        *(uint2*)&U[((w * 64) + qtt * 16 + l16) * 72 + mtd * 16 + l4 * 4] = u;
      }
    __syncthreads();
    // owner: q = q0 + w*16 + l16, d = l4*16 .. +16
    float sum[16];
#pragma unroll
    for (int j = 0; j < 16; j++) sum[j] = 0.f;
#pragma unroll
    for (int s = 0; s < 4; s++) {
      bf16x8 c0 = *(const bf16x8*)&U[((s * 64) + w * 16 + l16) * 72 + l4 * 16];
      bf16x8 c1 = *(const bf16x8*)&U[((s * 64) + w * 16 + l16) * 72 + l4 * 16 + 8];
#pragma unroll
      for (int j = 0; j < 8; j++) { sum[j] += (float)c0[j]; sum[8 + j] += (float)c1[j]; }
    }
    float invd = 1.0f / denom[w];
    if (phase == 0) {
#pragma unroll
      for (int j = 0; j < 16; j++) o_self[j] = sum[j] * invd;
    } else {
      long row = (long)b * 2048 + q0 + w * 16 + l16;
      bf16 out[16];
#pragma unroll
      for (int j = 0; j < 16; j++) out[j] = (bf16)(o_self[j] + sum[j] * invd);
      *(bf16x8*)&Y[row * 1024 + h * 64 + l4 * 16] = *(const bf16x8*)&out[0];
      *(bf16x8*)&Y[row * 1024 + h * 64 + l4 * 16 + 8] = *(const bf16x8*)&out[8];
    }
  }  // phase
}

extern "C" void kernel_launch(void* const* d_in, const int* in_sizes, int n_in,
                              void* d_out, int out_size, void* d_ws, size_t ws_size,
                              hipStream_t stream) {
  const float* x   = (const float*)d_in[0];
  const float* xc  = (const float*)d_in[1];
  const float* Wk  = (const float*)d_in[2];  const float* bk  = (const float*)d_in[3];
  const float* Wq  = (const float*)d_in[4];  const float* bq  = (const float*)d_in[5];
  const float* Wv  = (const float*)d_in[6];  const float* bv  = (const float*)d_in[7];
  const float* Wck = (const float*)d_in[8];  const float* bck = (const float*)d_in[9];
  const float* Wcq = (const float*)d_in[10]; const float* bcq = (const float*)d_in[11];
  const float* Wcv = (const float*)d_in[12]; const float* bcv = (const float*)d_in[13];
  const float* Wp  = (const float*)d_in[14]; const float* bp  = (const float*)d_in[15];

  char* ws = (char*)d_ws;
  const size_t MB = 1ull << 20;
  bf16*  WT_all = (bf16*)(ws + 0);         // [4096][1024]: Q|K|V|Qc
  bf16*  WC_all = (bf16*)(ws + 8 * MB);    // [2048][512]: Kc|Vc
  bf16*  WpT    = (bf16*)(ws + 10 * MB);   // [1024][1024]
  bf16*  xbf    = (bf16*)(ws + 12 * MB);   // [4096][1024]; Yb overlays after projections
  bf16*  Yb     = xbf;
  bf16*  xcbf   = (bf16*)(ws + 20 * MB);   // [1024][512]
  float* bias4  = (float*)(ws + 21 * MB);          // [4096]: bq|bk|bv|bcq
  float* biasc  = (float*)(ws + 21 * MB + 65536);  // [2048]: bck|bcv
  bf16*  QKQc   = (bf16*)(ws + 22 * MB);   // [4096][3072]: Q|K|Qc (compacted)
  bf16*  VtB    = (bf16*)(ws + 46 * MB);   // [2][16][64][2048]
  bf16*  KcB    = (bf16*)(ws + 54 * MB);   // [1024][1024]
  bf16*  VctB   = (bf16*)(ws + 56 * MB);   // [2][16][64][512]

  PrepArgs pa;
  pa.x = x; pa.xc = xc; pa.xbf = xbf; pa.xcbf = xcbf;
  pa.b4[0] = bq; pa.b4[1] = bk; pa.b4[2] = bv; pa.b4[3] = bcq;
  pa.bc[0] = bck; pa.bc[1] = bcv;
  pa.bias4 = bias4; pa.biasc = biasc;
  pa.W[0] = Wq;  pa.WT[0] = WT_all + 0ll * 1024 * 1024;
  pa.W[1] = Wk;  pa.WT[1] = WT_all + 1ll * 1024 * 1024;
  pa.W[2] = Wv;  pa.WT[2] = WT_all + 2ll * 1024 * 1024;
  pa.W[3] = Wcq; pa.WT[3] = WT_all + 3ll * 1024 * 1024;
  pa.W[4] = Wp;  pa.WT[4] = WpT;
  pa.W[5] = Wck; pa.WT[5] = WC_all + 0ll * 1024 * 512;
  pa.W[6] = Wcv; pa.WT[6] = WC_all + 1ll * 1024 * 512;
  prep_kernel<<<10776, 256, 0, stream>>>(pa);

  // fused QKV+Qc projection: N=4096; V section [2048,3072) -> VtB transposed;
  // Q/Qc columns pre-scaled by 0.125*log2e for exp2-softmax
  gemm128<bf16><<<dim3(32, 32), 256, 0, stream>>>(xbf, WT_all, bias4, QKQc,
                                                  4096, 4096, 1024, 3072,
                                                  VtB, 2048, 3072, 2048, 11, 1);
  // fused cross K+V: N=2048; Vc section [1024,2048) -> VctB transposed
  gemm128<bf16><<<dim3(16, 8), 256, 0, stream>>>(xcbf, WC_all, biasc, KcB,
                                                 1024, 2048, 512, 1024,
                                                 VctB, 1024, 2048, 512, 9, 0);

  attn_kernel<<<dim3(32, 32), 256, 0, stream>>>(QKQc, VtB, KcB, VctB, Yb);

  gemm128<float><<<dim3(8, 32), 256, 0, stream>>>(Yb, WpT, bp, (float*)d_out,
                                                  4096, 1024, 1024, 1024,
                                                  nullptr, -1, -1, 0, 0, 0);
}

// Round 8
// 317.599 us; speedup vs baseline: 1.2153x; 1.2153x over previous
//
#include <hip/hip_runtime.h>
#include <hip/hip_bf16.h>
#include <type_traits>

typedef __bf16 bf16;
typedef __bf16 bf16x8 __attribute__((ext_vector_type(8)));
typedef float floatx4 __attribute__((ext_vector_type(4)));

#if __has_builtin(__builtin_amdgcn_exp2f)
#define EXP2(x) __builtin_amdgcn_exp2f(x)
#else
#define EXP2(x) exp2f(x)
#endif

#define QSCALE 0.18033688011112043f  // 0.125 * log2(e)

__device__ __forceinline__ void glds16(const bf16* g, bf16* l) {
  __builtin_amdgcn_global_load_lds((const __attribute__((address_space(1))) void*)g,
                                   (__attribute__((address_space(3))) void*)l, 16, 0, 0);
}

__device__ __forceinline__ unsigned pack_bf16(float a, float b) {
  unsigned short ua = __builtin_bit_cast(unsigned short, (bf16)a);
  unsigned short ub = __builtin_bit_cast(unsigned short, (bf16)b);
  return (unsigned)ua | ((unsigned)ub << 16);
}

// ---------------- fused preprocessing: converts, bias concat, 7 weight transposes --
struct PrepArgs {
  const float* x; const float* xc;
  bf16* xbf; bf16* xcbf;
  const float* b4[4];   // bq,bk,bv,bcq
  const float* bc[2];   // bck,bcv
  float* bias4; float* biasc;
  const float* W[7];    // Wq,Wk,Wv,Wcq,Wp,Wck,Wcv
  bf16* WT[7];
};

__global__ __launch_bounds__(256) void prep_kernel(PrepArgs a) {
  __shared__ bf16 tsh[32][33];
  const int bx = blockIdx.x, tid = threadIdx.x;
  if (bx < 4096) {  // x fp32->bf16
    int i = bx * 256 + tid;
    float4 f = ((const float4*)a.x)[i];
    bf16 t[4] = {(bf16)f.x, (bf16)f.y, (bf16)f.z, (bf16)f.w};
    *(uint2*)&a.xbf[(long)i * 4] = *(const uint2*)t;
  } else if (bx < 4608) {  // xc fp32->bf16
    int i = (bx - 4096) * 256 + tid;
    float4 f = ((const float4*)a.xc)[i];
    bf16 t[4] = {(bf16)f.x, (bf16)f.y, (bf16)f.z, (bf16)f.w};
    *(uint2*)&a.xcbf[(long)i * 4] = *(const uint2*)t;
  } else if (bx < 4632) {  // bias concat
    int lb = bx - 4608;
    if (lb < 16) { int i = lb * 256 + tid; a.bias4[i] = a.b4[i >> 10][i & 1023]; }
    else         { int i = (lb - 16) * 256 + tid; a.biasc[i] = a.bc[i >> 10][i & 1023]; }
  } else {  // weight transpose [R,1024] fp32 -> [1024,R] bf16
    int t = bx - 4632, w, R, bxw, byw;
    if (t < 5120) { w = t >> 10; R = 1024; int l = t & 1023; bxw = l & 31; byw = l >> 5; }
    else { int t2 = t - 5120; w = 5 + (t2 >> 9); R = 512; int l = t2 & 511; bxw = l & 31; byw = l >> 5; }
    const float* in = a.W[w];
    bf16* out = a.WT[w];
    int tx = tid & 31, ty = tid >> 5;
    int c = bxw * 32 + tx;
#pragma unroll
    for (int i = 0; i < 4; i++) {
      int r = byw * 32 + ty + i * 8;
      tsh[ty + i * 8][tx] = (bf16)in[(long)r * 1024 + c];
    }
    __syncthreads();
    int oc = byw * 32 + tx;
#pragma unroll
    for (int i = 0; i < 4; i++) {
      int orr = bxw * 32 + ty + i * 8;
      out[(long)orr * R + oc] = tsh[tx][ty + i * 8];
    }
  }
}

// ---------------- 128x128 m97-style GEMM: C[M,N] = A[M,K] @ Bt[N,K]^T + bias -------
// qflag: scale Q/Qc columns (col<1024 || col>=3072) by QSCALE in the epilogue.
template <typename OutT>
__global__ __launch_bounds__(256, 3) void gemm128(const bf16* __restrict__ A,
                                                  const bf16* __restrict__ Bt,
                                                  const float* __restrict__ bias,
                                                  OutT* __restrict__ C,
                                                  int M, int N, int K, int ldc,
                                                  bf16* __restrict__ Vt,
                                                  int vcol0, int vcol1, int Lt, int tok_shift,
                                                  int qflag) {
  __shared__ alignas(16) bf16 As[128 * 32];
  __shared__ alignas(16) bf16 Bs[128 * 32];
  const int tid = threadIdx.x, wave = tid >> 6, lane = tid & 63;
  const int l16 = lane & 15, l4 = lane >> 4;
  const int wm = wave & 1, wn = wave >> 1;
  const int n0 = blockIdx.x * 128, m0 = blockIdx.y * 128;
  const int lrow = lane >> 2, lch = (lane & 3) * 8;

  floatx4 acc[4][4];
#pragma unroll
  for (int mt = 0; mt < 4; mt++)
#pragma unroll
    for (int nt = 0; nt < 4; nt++) acc[mt][nt] = (floatx4){0.f, 0.f, 0.f, 0.f};

  const bf16* Ag = A + (long)(m0 + wave * 32 + lrow) * K + lch;
  const bf16* Bg = Bt + (long)(n0 + wave * 32 + lrow) * K + lch;
  bf16* Al = &As[(wave * 32) * 32];
  bf16* Bl = &Bs[(wave * 32) * 32];

  for (int k0 = 0; k0 < K; k0 += 32) {
    __syncthreads();
    glds16(Ag + k0, Al);
    glds16(Ag + k0 + (long)16 * K, Al + 16 * 32);
    glds16(Bg + k0, Bl);
    glds16(Bg + k0 + (long)16 * K, Bl + 16 * 32);
    __syncthreads();
    bf16x8 a[4], b[4];
#pragma unroll
    for (int mt = 0; mt < 4; mt++) a[mt] = *(const bf16x8*)&As[(wm * 64 + mt * 16 + l16) * 32 + l4 * 8];
#pragma unroll
    for (int nt = 0; nt < 4; nt++) b[nt] = *(const bf16x8*)&Bs[(wn * 64 + nt * 16 + l16) * 32 + l4 * 8];
#pragma unroll
    for (int mt = 0; mt < 4; mt++)
#pragma unroll
      for (int nt = 0; nt < 4; nt++)
        acc[mt][nt] = __builtin_amdgcn_mfma_f32_16x16x32_bf16(a[mt], b[nt], acc[mt][nt], 0, 0, 0);
  }

  const bool vpath = (vcol0 >= 0) && (n0 >= vcol0) && (n0 < vcol1);
  if (!vpath) {
    const int coladj = (vcol0 >= 0 && n0 >= vcol1) ? (vcol1 - vcol0) : 0;
#pragma unroll
    for (int nt = 0; nt < 4; nt++) {
      int col = n0 + wn * 64 + nt * 16 + l16;
      float bv = bias[col];
      float sc = (qflag && (col < 1024 || col >= 3072)) ? QSCALE : 1.0f;
#pragma unroll
      for (int mt = 0; mt < 4; mt++)
#pragma unroll
        for (int r = 0; r < 4; r++) {
          int row = m0 + wm * 64 + mt * 16 + l4 * 4 + r;
          float v = (acc[mt][nt][r] + bv) * sc;
          if constexpr (std::is_same_v<OutT, float>) C[(long)row * ldc + col - coladj] = v;
          else                                       C[(long)row * ldc + col - coladj] = (bf16)v;
        }
    }
  } else {
#pragma unroll
    for (int nt = 0; nt < 4; nt++) {
      int col = n0 + wn * 64 + nt * 16 + l16;
      int c = col - vcol0, hh = c >> 6, dd = c & 63;
      float bv = bias[col];
#pragma unroll
      for (int mt = 0; mt < 4; mt++) {
        int t0 = m0 + wm * 64 + mt * 16 + l4 * 4;
        int bb = t0 >> tok_shift, t = t0 & ((1 << tok_shift) - 1);
        bf16 tmp[4];
#pragma unroll
        for (int r = 0; r < 4; r++) tmp[r] = (bf16)(acc[mt][nt][r] + bv);
        *(uint2*)&Vt[(((long)bb * 16 + hh) * 64 + dd) * Lt + t] = *(const uint2*)tmp;
      }
    }
  }
}

// ---------------- barrier-free fused self(causal)+cross flash attention ------------
// grid (32 bh, 32 qt'): qt = 31-qt' (heavy first); bh-major => (b,h) K/V stays in one
// XCD's L2 (FETCH 20 MB vs 430 MB logical -> L2-resident, so no K prefetch needed).
// Keys striped across waves; per-wave online softmax; flash-combine once/phase.
// Register diet for 3 waves/SIMD: no K dbuf, pd streamed to LDS, o_self in LDS.
__global__ __launch_bounds__(256, 3) void attn_kernel(const bf16* __restrict__ QKQc,
                                                      const bf16* __restrict__ VtB,
                                                      const bf16* __restrict__ KcB,
                                                      const bf16* __restrict__ VctB,
                                                      bf16* __restrict__ Y) {
  __shared__ float2 Mbuf[4][4][16];           // [wave][qt][l16] = (m, l)
  __shared__ alignas(16) bf16 U[4 * 64 * 72]; // Obuf [w][64q][72d] / P slabs [w][64q][44k]
  __shared__ alignas(16) bf16 Osf[64 * 72];   // phase-0 output (frees 16 VGPRs)
  const int tid = threadIdx.x, w = tid >> 6, lane = tid & 63;
  const int l16 = lane & 15, l4 = lane >> 4;
  const int bh = blockIdx.x, h = bh & 15, b = bh >> 4;
  const int qt = 31 - (int)blockIdx.y;
  const int q0 = qt * 64;
  const int wk = w * 32;                      // wave's key offset inside a 128-tile
  const float NEG = -1e30f;
  bf16* Pw = U + w * (64 * 44);               // wave-private, stride 44 (conflict-free)

  for (int phase = 0; phase < 2; phase++) {
    const bf16 *Qb, *Kb, *Vtb;
    int kstr, vtstr, nkt;
    if (phase == 0) {
      Qb = QKQc + (long)b * 2048 * 3072 + h * 64;
      Kb = Qb + 1024;                              kstr = 3072;
      Vtb = VtB + ((long)b * 16 + h) * 64 * 2048;  vtstr = 2048;
      nkt = (qt + 2) >> 1;
    } else {
      Qb = QKQc + (long)b * 2048 * 3072 + h * 64 + 2048;
      Kb = KcB + (long)b * 512 * 1024 + h * 64;    kstr = 1024;
      Vtb = VctB + ((long)b * 16 + h) * 64 * 512;  vtstr = 512;
      nkt = 4;
    }

    __syncthreads();  // U/Mbuf safe to reuse across phases

    // Q B-frags for the whole phase (scale pre-folded in GEMM epilogue)
    bf16x8 qf[4][2];
#pragma unroll
    for (int qtt = 0; qtt < 4; qtt++) {
      const bf16* qp = Qb + (long)(q0 + qtt * 16 + l16) * 3072 + l4 * 8;
#pragma unroll
      for (int ds = 0; ds < 2; ds++) qf[qtt][ds] = *(const bf16x8*)(qp + ds * 32);
    }

    float m_i[4], l_i[4];
#pragma unroll
    for (int qtt = 0; qtt < 4; qtt++) { m_i[qtt] = NEG; l_i[qtt] = 0.f; }
    floatx4 oacc[4][4];  // [mtd (d)][qt]: O^T, col=q=l16, row=d=l4*4+r
#pragma unroll
    for (int mtd = 0; mtd < 4; mtd++)
#pragma unroll
      for (int qtt = 0; qtt < 4; qtt++) oacc[mtd][qtt] = (floatx4){0.f, 0.f, 0.f, 0.f};

    for (int kt = 0; kt < nkt; kt++) {
      const int kbase = kt * 128 + wk;
      // K + V^T loads issued back-to-back (L2-hot); K consumed first
      bf16x8 kc[2][2];
#pragma unroll
      for (int mt = 0; mt < 2; mt++)
#pragma unroll
        for (int ds = 0; ds < 2; ds++)
          kc[mt][ds] = *(const bf16x8*)(Kb + (long)(kbase + mt * 16 + l16) * kstr + ds * 32 + l4 * 8);
      bf16x8 vc[4];
#pragma unroll
      for (int mtd = 0; mtd < 4; mtd++)
        vc[mtd] = *(const bf16x8*)(Vtb + (long)(mtd * 16 + l16) * vtstr + kbase + l4 * 8);

      // S^T tiles: A = K rows (m=key), B = Q rows (n=q)
      floatx4 sacc[2][4];
#pragma unroll
      for (int mt = 0; mt < 2; mt++)
#pragma unroll
        for (int qtt = 0; qtt < 4; qtt++) sacc[mt][qtt] = (floatx4){0.f, 0.f, 0.f, 0.f};
#pragma unroll
      for (int ds = 0; ds < 2; ds++)
#pragma unroll
        for (int mt = 0; mt < 2; mt++)
#pragma unroll
          for (int qtt = 0; qtt < 4; qtt++)
            sacc[mt][qtt] = __builtin_amdgcn_mfma_f32_16x16x32_bf16(kc[mt][ds], qf[qtt][ds], sacc[mt][qtt], 0, 0, 0);

      // causal mask (finite NEG; only last self tile straddles)
      if (phase == 0 && kt == nkt - 1) {
#pragma unroll
        for (int mt = 0; mt < 2; mt++) {
          int keyb = kbase + mt * 16 + l4 * 4;
#pragma unroll
          for (int qtt = 0; qtt < 4; qtt++) {
            int q = q0 + qtt * 16 + l16;
#pragma unroll
            for (int r = 0; r < 4; r++)
              if (keyb + r > q) sacc[mt][qtt][r] = NEG;
          }
        }
      }

      // per-wave online softmax; P streamed to wave-private slab immediately
      float alpha[4];
      int changed = 0;
#pragma unroll
      for (int qtt = 0; qtt < 4; qtt++) {
        float mx = fmaxf(fmaxf(fmaxf(sacc[0][qtt][0], sacc[0][qtt][1]), fmaxf(sacc[0][qtt][2], sacc[0][qtt][3])),
                         fmaxf(fmaxf(sacc[1][qtt][0], sacc[1][qtt][1]), fmaxf(sacc[1][qtt][2], sacc[1][qtt][3])));
        mx = fmaxf(mx, __shfl_xor(mx, 16));
        mx = fmaxf(mx, __shfl_xor(mx, 32));
        mx = fmaxf(mx, m_i[qtt]);
        alpha[qtt] = EXP2(m_i[qtt] - mx);
        changed |= (mx > m_i[qtt]) ? 1 : 0;
        m_i[qtt] = mx;
        float rs = 0.f;
#pragma unroll
        for (int mt = 0; mt < 2; mt++) {
          float p0 = EXP2(sacc[mt][qtt][0] - mx), p1 = EXP2(sacc[mt][qtt][1] - mx);
          float p2 = EXP2(sacc[mt][qtt][2] - mx), p3 = EXP2(sacc[mt][qtt][3] - mx);
          rs += (p0 + p1) + (p2 + p3);
          uint2 u = {pack_bf16(p0, p1), pack_bf16(p2, p3)};
          *(uint2*)&Pw[(qtt * 16 + l16) * 44 + mt * 16 + l4 * 4] = u;
        }
        rs += __shfl_xor(rs, 16);
        rs += __shfl_xor(rs, 32);
        l_i[qtt] = l_i[qtt] * alpha[qtt] + rs;
      }
      if (__any(changed)) {
#pragma unroll
        for (int mtd = 0; mtd < 4; mtd++)
#pragma unroll
          for (int qtt = 0; qtt < 4; qtt++)
#pragma unroll
            for (int r = 0; r < 4; r++) oacc[mtd][qtt][r] *= alpha[qtt];
      }

      // O^T += V^T · P^T (wave-private slab; lgkmcnt ordering, no barrier)
#pragma unroll
      for (int qtt = 0; qtt < 4; qtt++) {
        bf16x8 pf = *(const bf16x8*)&Pw[(qtt * 16 + l16) * 44 + l4 * 8];
#pragma unroll
        for (int mtd = 0; mtd < 4; mtd++)
          oacc[mtd][qtt] = __builtin_amdgcn_mfma_f32_16x16x32_bf16(vc[mtd], pf, oacc[mtd][qtt], 0, 0, 0);
      }
    }  // kt

    // ---- flash-combine across the 4 waves ----
    if (l4 == 0) {
#pragma unroll
      for (int qtt = 0; qtt < 4; qtt++) Mbuf[w][qtt][l16] = make_float2(m_i[qtt], l_i[qtt]);
    }
    __syncthreads();
    float myscale[4], denom[4];
#pragma unroll
    for (int qtt = 0; qtt < 4; qtt++) {
      float2 s0 = Mbuf[0][qtt][l16], s1 = Mbuf[1][qtt][l16];
      float2 s2 = Mbuf[2][qtt][l16], s3 = Mbuf[3][qtt][l16];
      float M = fmaxf(fmaxf(s0.x, s1.x), fmaxf(s2.x, s3.x));
      denom[qtt] = EXP2(s0.x - M) * s0.y + EXP2(s1.x - M) * s1.y +
                   EXP2(s2.x - M) * s2.y + EXP2(s3.x - M) * s3.y;
      myscale[qtt] = EXP2(m_i[qtt] - M);
    }
    // scaled O^T partials (bf16) -> Obuf[w][q][d]
#pragma unroll
    for (int qtt = 0; qtt < 4; qtt++)
#pragma unroll
      for (int mtd = 0; mtd < 4; mtd++) {
        float s = myscale[qtt];
        uint2 u = {pack_bf16(oacc[mtd][qtt][0] * s, oacc[mtd][qtt][1] * s),
                   pack_bf16(oacc[mtd][qtt][2] * s, oacc[mtd][qtt][3] * s)};
        *(uint2*)&U[((w * 64) + qtt * 16 + l16) * 72 + mtd * 16 + l4 * 4] = u;
      }
    __syncthreads();
    // owner: q = q0 + w*16 + l16, d = l4*16 .. +16
    float sum[16];
#pragma unroll
    for (int j = 0; j < 16; j++) sum[j] = 0.f;
#pragma unroll
    for (int s = 0; s < 4; s++) {
      bf16x8 c0 = *(const bf16x8*)&U[((s * 64) + w * 16 + l16) * 72 + l4 * 16];
      bf16x8 c1 = *(const bf16x8*)&U[((s * 64) + w * 16 + l16) * 72 + l4 * 16 + 8];
#pragma unroll
      for (int j = 0; j < 8; j++) { sum[j] += (float)c0[j]; sum[8 + j] += (float)c1[j]; }
    }
    float invd = 1.0f / denom[w];
    if (phase == 0) {
      bf16 t[16];
#pragma unroll
      for (int j = 0; j < 16; j++) t[j] = (bf16)(sum[j] * invd);
      *(bf16x8*)&Osf[(w * 16 + l16) * 72 + l4 * 16] = *(const bf16x8*)&t[0];
      *(bf16x8*)&Osf[(w * 16 + l16) * 72 + l4 * 16 + 8] = *(const bf16x8*)&t[8];
    } else {
      bf16x8 p0 = *(const bf16x8*)&Osf[(w * 16 + l16) * 72 + l4 * 16];
      bf16x8 p1 = *(const bf16x8*)&Osf[(w * 16 + l16) * 72 + l4 * 16 + 8];
      long row = (long)b * 2048 + q0 + w * 16 + l16;
      bf16 out[16];
#pragma unroll
      for (int j = 0; j < 8; j++) {
        out[j] = (bf16)((float)p0[j] + sum[j] * invd);
        out[8 + j] = (bf16)((float)p1[j] + sum[8 + j] * invd);
      }
      *(bf16x8*)&Y[row * 1024 + h * 64 + l4 * 16] = *(const bf16x8*)&out[0];
      *(bf16x8*)&Y[row * 1024 + h * 64 + l4 * 16 + 8] = *(const bf16x8*)&out[8];
    }
  }  // phase
}

extern "C" void kernel_launch(void* const* d_in, const int* in_sizes, int n_in,
                              void* d_out, int out_size, void* d_ws, size_t ws_size,
                              hipStream_t stream) {
  const float* x   = (const float*)d_in[0];
  const float* xc  = (const float*)d_in[1];
  const float* Wk  = (const float*)d_in[2];  const float* bk  = (const float*)d_in[3];
  const float* Wq  = (const float*)d_in[4];  const float* bq  = (const float*)d_in[5];
  const float* Wv  = (const float*)d_in[6];  const float* bv  = (const float*)d_in[7];
  const float* Wck = (const float*)d_in[8];  const float* bck = (const float*)d_in[9];
  const float* Wcq = (const float*)d_in[10]; const float* bcq = (const float*)d_in[11];
  const float* Wcv = (const float*)d_in[12]; const float* bcv = (const float*)d_in[13];
  const float* Wp  = (const float*)d_in[14]; const float* bp  = (const float*)d_in[15];

  char* ws = (char*)d_ws;
  const size_t MB = 1ull << 20;
  bf16*  WT_all = (bf16*)(ws + 0);         // [4096][1024]: Q|K|V|Qc
  bf16*  WC_all = (bf16*)(ws + 8 * MB);    // [2048][512]: Kc|Vc
  bf16*  WpT    = (bf16*)(ws + 10 * MB);   // [1024][1024]
  bf16*  xbf    = (bf16*)(ws + 12 * MB);   // [4096][1024]; Yb overlays after projections
  bf16*  Yb     = xbf;
  bf16*  xcbf   = (bf16*)(ws + 20 * MB);   // [1024][512]
  float* bias4  = (float*)(ws + 21 * MB);          // [4096]: bq|bk|bv|bcq
  float* biasc  = (float*)(ws + 21 * MB + 65536);  // [2048]: bck|bcv
  bf16*  QKQc   = (bf16*)(ws + 22 * MB);   // [4096][3072]: Q|K|Qc (compacted)
  bf16*  VtB    = (bf16*)(ws + 46 * MB);   // [2][16][64][2048]
  bf16*  KcB    = (bf16*)(ws + 54 * MB);   // [1024][1024]
  bf16*  VctB   = (bf16*)(ws + 56 * MB);   // [2][16][64][512]

  PrepArgs pa;
  pa.x = x; pa.xc = xc; pa.xbf = xbf; pa.xcbf = xcbf;
  pa.b4[0] = bq; pa.b4[1] = bk; pa.b4[2] = bv; pa.b4[3] = bcq;
  pa.bc[0] = bck; pa.bc[1] = bcv;
  pa.bias4 = bias4; pa.biasc = biasc;
  pa.W[0] = Wq;  pa.WT[0] = WT_all + 0ll * 1024 * 1024;
  pa.W[1] = Wk;  pa.WT[1] = WT_all + 1ll * 1024 * 1024;
  pa.W[2] = Wv;  pa.WT[2] = WT_all + 2ll * 1024 * 1024;
  pa.W[3] = Wcq; pa.WT[3] = WT_all + 3ll * 1024 * 1024;
  pa.W[4] = Wp;  pa.WT[4] = WpT;
  pa.W[5] = Wck; pa.WT[5] = WC_all + 0ll * 1024 * 512;
  pa.W[6] = Wcv; pa.WT[6] = WC_all + 1ll * 1024 * 512;
  prep_kernel<<<10776, 256, 0, stream>>>(pa);

  // fused QKV+Qc projection: N=4096; V section [2048,3072) -> VtB transposed;
  // Q/Qc columns pre-scaled by 0.125*log2e for exp2-softmax
  gemm128<bf16><<<dim3(32, 32), 256, 0, stream>>>(xbf, WT_all, bias4, QKQc,
                                                  4096, 4096, 1024, 3072,
                                                  VtB, 2048, 3072, 2048, 11, 1);
  // fused cross K+V: N=2048; Vc section [1024,2048) -> VctB transposed
  gemm128<bf16><<<dim3(16, 8), 256, 0, stream>>>(xcbf, WC_all, biasc, KcB,
                                                 1024, 2048, 512, 1024,
                                                 VctB, 1024, 2048, 512, 9, 0);

  attn_kernel<<<dim3(32, 32), 256, 0, stream>>>(QKQc, VtB, KcB, VctB, Yb);

  gemm128<float><<<dim3(8, 32), 256, 0, stream>>>(Yb, WpT, bp, (float*)d_out,
                                                  4096, 1024, 1024, 1024,
                                                  nullptr, -1, -1, 0, 0, 0);
}

// Round 9
// 263.075 us; speedup vs baseline: 1.4672x; 1.2073x over previous
//
#include <hip/hip_runtime.h>
#include <hip/hip_bf16.h>
#include <type_traits>

typedef __bf16 bf16;
typedef __bf16 bf16x8 __attribute__((ext_vector_type(8)));
typedef float floatx4 __attribute__((ext_vector_type(4)));

#if __has_builtin(__builtin_amdgcn_exp2f)
#define EXP2(x) __builtin_amdgcn_exp2f(x)
#else
#define EXP2(x) exp2f(x)
#endif

#define QSCALE 0.18033688011112043f  // 0.125 * log2(e)

__device__ __forceinline__ void glds16(const bf16* g, bf16* l) {
  __builtin_amdgcn_global_load_lds((const __attribute__((address_space(1))) void*)g,
                                   (__attribute__((address_space(3))) void*)l, 16, 0, 0);
}

__device__ __forceinline__ unsigned pack_bf16(float a, float b) {
  unsigned short ua = __builtin_bit_cast(unsigned short, (bf16)a);
  unsigned short ub = __builtin_bit_cast(unsigned short, (bf16)b);
  return (unsigned)ua | ((unsigned)ub << 16);
}

// ---------------- fused preprocessing: converts, bias concat, 7 weight transposes --
struct PrepArgs {
  const float* x; const float* xc;
  bf16* xbf; bf16* xcbf;
  const float* b4[4];   // bq,bk,bv,bcq
  const float* bc[2];   // bck,bcv
  float* bias4; float* biasc;
  const float* W[7];    // Wq,Wk,Wv,Wcq,Wp,Wck,Wcv
  bf16* WT[7];
};

__global__ __launch_bounds__(256) void prep_kernel(PrepArgs a) {
  __shared__ bf16 tsh[32][33];
  const int bx = blockIdx.x, tid = threadIdx.x;
  if (bx < 4096) {  // x fp32->bf16
    int i = bx * 256 + tid;
    float4 f = ((const float4*)a.x)[i];
    bf16 t[4] = {(bf16)f.x, (bf16)f.y, (bf16)f.z, (bf16)f.w};
    *(uint2*)&a.xbf[(long)i * 4] = *(const uint2*)t;
  } else if (bx < 4608) {  // xc fp32->bf16
    int i = (bx - 4096) * 256 + tid;
    float4 f = ((const float4*)a.xc)[i];
    bf16 t[4] = {(bf16)f.x, (bf16)f.y, (bf16)f.z, (bf16)f.w};
    *(uint2*)&a.xcbf[(long)i * 4] = *(const uint2*)t;
  } else if (bx < 4632) {  // bias concat
    int lb = bx - 4608;
    if (lb < 16) { int i = lb * 256 + tid; a.bias4[i] = a.b4[i >> 10][i & 1023]; }
    else         { int i = (lb - 16) * 256 + tid; a.biasc[i] = a.bc[i >> 10][i & 1023]; }
  } else {  // weight transpose [R,1024] fp32 -> [1024,R] bf16
    int t = bx - 4632, w, R, bxw, byw;
    if (t < 5120) { w = t >> 10; R = 1024; int l = t & 1023; bxw = l & 31; byw = l >> 5; }
    else { int t2 = t - 5120; w = 5 + (t2 >> 9); R = 512; int l = t2 & 511; bxw = l & 31; byw = l >> 5; }
    const float* in = a.W[w];
    bf16* out = a.WT[w];
    int tx = tid & 31, ty = tid >> 5;
    int c = bxw * 32 + tx;
#pragma unroll
    for (int i = 0; i < 4; i++) {
      int r = byw * 32 + ty + i * 8;
      tsh[ty + i * 8][tx] = (bf16)in[(long)r * 1024 + c];
    }
    __syncthreads();
    int oc = byw * 32 + tx;
#pragma unroll
    for (int i = 0; i < 4; i++) {
      int orr = bxw * 32 + ty + i * 8;
      out[(long)orr * R + oc] = tsh[tx][ty + i * 8];
    }
  }
}

// ---------------- 128x128 m97-style GEMM: C[M,N] = A[M,K] @ Bt[N,K]^T + bias -------
// qflag: scale Q/Qc columns (col<1024 || col>=3072) by QSCALE in the epilogue.
template <typename OutT>
__global__ __launch_bounds__(256, 3) void gemm128(const bf16* __restrict__ A,
                                                  const bf16* __restrict__ Bt,
                                                  const float* __restrict__ bias,
                                                  OutT* __restrict__ C,
                                                  int M, int N, int K, int ldc,
                                                  bf16* __restrict__ Vt,
                                                  int vcol0, int vcol1, int Lt, int tok_shift,
                                                  int qflag) {
  __shared__ alignas(16) bf16 As[128 * 32];
  __shared__ alignas(16) bf16 Bs[128 * 32];
  const int tid = threadIdx.x, wave = tid >> 6, lane = tid & 63;
  const int l16 = lane & 15, l4 = lane >> 4;
  const int wm = wave & 1, wn = wave >> 1;
  const int n0 = blockIdx.x * 128, m0 = blockIdx.y * 128;
  const int lrow = lane >> 2, lch = (lane & 3) * 8;

  floatx4 acc[4][4];
#pragma unroll
  for (int mt = 0; mt < 4; mt++)
#pragma unroll
    for (int nt = 0; nt < 4; nt++) acc[mt][nt] = (floatx4){0.f, 0.f, 0.f, 0.f};

  const bf16* Ag = A + (long)(m0 + wave * 32 + lrow) * K + lch;
  const bf16* Bg = Bt + (long)(n0 + wave * 32 + lrow) * K + lch;
  bf16* Al = &As[(wave * 32) * 32];
  bf16* Bl = &Bs[(wave * 32) * 32];

  for (int k0 = 0; k0 < K; k0 += 32) {
    __syncthreads();
    glds16(Ag + k0, Al);
    glds16(Ag + k0 + (long)16 * K, Al + 16 * 32);
    glds16(Bg + k0, Bl);
    glds16(Bg + k0 + (long)16 * K, Bl + 16 * 32);
    __syncthreads();
    bf16x8 a[4], b[4];
#pragma unroll
    for (int mt = 0; mt < 4; mt++) a[mt] = *(const bf16x8*)&As[(wm * 64 + mt * 16 + l16) * 32 + l4 * 8];
#pragma unroll
    for (int nt = 0; nt < 4; nt++) b[nt] = *(const bf16x8*)&Bs[(wn * 64 + nt * 16 + l16) * 32 + l4 * 8];
#pragma unroll
    for (int mt = 0; mt < 4; mt++)
#pragma unroll
      for (int nt = 0; nt < 4; nt++)
        acc[mt][nt] = __builtin_amdgcn_mfma_f32_16x16x32_bf16(a[mt], b[nt], acc[mt][nt], 0, 0, 0);
  }

  const bool vpath = (vcol0 >= 0) && (n0 >= vcol0) && (n0 < vcol1);
  if (!vpath) {
    const int coladj = (vcol0 >= 0 && n0 >= vcol1) ? (vcol1 - vcol0) : 0;
#pragma unroll
    for (int nt = 0; nt < 4; nt++) {
      int col = n0 + wn * 64 + nt * 16 + l16;
      float bv = bias[col];
      float sc = (qflag && (col < 1024 || col >= 3072)) ? QSCALE : 1.0f;
#pragma unroll
      for (int mt = 0; mt < 4; mt++)
#pragma unroll
        for (int r = 0; r < 4; r++) {
          int row = m0 + wm * 64 + mt * 16 + l4 * 4 + r;
          float v = (acc[mt][nt][r] + bv) * sc;
          if constexpr (std::is_same_v<OutT, float>) C[(long)row * ldc + col - coladj] = v;
          else                                       C[(long)row * ldc + col - coladj] = (bf16)v;
        }
    }
  } else {
#pragma unroll
    for (int nt = 0; nt < 4; nt++) {
      int col = n0 + wn * 64 + nt * 16 + l16;
      int c = col - vcol0, hh = c >> 6, dd = c & 63;
      float bv = bias[col];
#pragma unroll
      for (int mt = 0; mt < 4; mt++) {
        int t0 = m0 + wm * 64 + mt * 16 + l4 * 4;
        int bb = t0 >> tok_shift, t = t0 & ((1 << tok_shift) - 1);
        bf16 tmp[4];
#pragma unroll
        for (int r = 0; r < 4; r++) tmp[r] = (bf16)(acc[mt][nt][r] + bv);
        *(uint2*)&Vt[(((long)bb * 16 + hh) * 64 + dd) * Lt + t] = *(const uint2*)tmp;
      }
    }
  }
}

// ---------------- barrier-free fused self(causal)+cross flash attention ------------
// Round-6 structure verbatim (proven 78 us, zero spills at (256,2)) with two verified
// deltas: P slab stride 48->44 (conflicts 5.7M->0.8M) and Q pre-scaled in GEMM.
// grid (32 bh, 32 qt'): qt = 31-qt' (heavy first); bh-major => (b,h) K/V in one XCD L2.
// Keys striped across waves; per-wave online softmax; flash-combine once/phase.
__global__ __launch_bounds__(256, 2) void attn_kernel(const bf16* __restrict__ QKQc,
                                                      const bf16* __restrict__ VtB,
                                                      const bf16* __restrict__ KcB,
                                                      const bf16* __restrict__ VctB,
                                                      bf16* __restrict__ Y) {
  __shared__ float2 Mbuf[4][4][16];           // [wave][qt][l16] = (m, l)
  __shared__ alignas(16) bf16 U[4 * 64 * 72]; // Obuf [w][64q][72d] / P slabs [w][64q][44k]
  const int tid = threadIdx.x, w = tid >> 6, lane = tid & 63;
  const int l16 = lane & 15, l4 = lane >> 4;
  const int bh = blockIdx.x, h = bh & 15, b = bh >> 4;
  const int qt = 31 - (int)blockIdx.y;
  const int q0 = qt * 64;
  const int wk = w * 32;                      // wave's key offset inside a 128-tile
  const float NEG = -1e30f;
  bf16* Pw = U + w * (64 * 44);               // wave-private, stride 44 (conflict-free)

  float o_self[16];

  for (int phase = 0; phase < 2; phase++) {
    const bf16 *Qb, *Kb, *Vtb;
    int kstr, vtstr, nkt;
    if (phase == 0) {
      Qb = QKQc + (long)b * 2048 * 3072 + h * 64;
      Kb = Qb + 1024;                              kstr = 3072;
      Vtb = VtB + ((long)b * 16 + h) * 64 * 2048;  vtstr = 2048;
      nkt = (qt + 2) >> 1;
    } else {
      Qb = QKQc + (long)b * 2048 * 3072 + h * 64 + 2048;
      Kb = KcB + (long)b * 512 * 1024 + h * 64;    kstr = 1024;
      Vtb = VctB + ((long)b * 16 + h) * 64 * 512;  vtstr = 512;
      nkt = 4;
    }

    __syncthreads();  // U/Mbuf safe to reuse across phases

    // Q B-frags for the whole phase (scale pre-folded in GEMM epilogue)
    bf16x8 qf[4][2];
#pragma unroll
    for (int qtt = 0; qtt < 4; qtt++) {
      const bf16* qp = Qb + (long)(q0 + qtt * 16 + l16) * 3072 + l4 * 8;
#pragma unroll
      for (int ds = 0; ds < 2; ds++) qf[qtt][ds] = *(const bf16x8*)(qp + ds * 32);
    }

    float m_i[4], l_i[4];
#pragma unroll
    for (int qtt = 0; qtt < 4; qtt++) { m_i[qtt] = NEG; l_i[qtt] = 0.f; }
    floatx4 oacc[4][4];  // [mtd (d)][qt]: O^T, col=q=l16, row=d=l4*4+r
#pragma unroll
    for (int mtd = 0; mtd < 4; mtd++)
#pragma unroll
      for (int qtt = 0; qtt < 4; qtt++) oacc[mtd][qtt] = (floatx4){0.f, 0.f, 0.f, 0.f};

    // prefetch K tile 0 (wave's own 32 keys)
    bf16x8 kc[2][2], kn[2][2];
#pragma unroll
    for (int mt = 0; mt < 2; mt++)
#pragma unroll
      for (int ds = 0; ds < 2; ds++)
        kc[mt][ds] = *(const bf16x8*)(Kb + (long)(wk + mt * 16 + l16) * kstr + ds * 32 + l4 * 8);

    for (int kt = 0; kt < nkt; kt++) {
      const int kbase = kt * 128 + wk;
      // V^T for this tile (consumed at iteration end -> latency hidden)
      bf16x8 vc[4];
#pragma unroll
      for (int mtd = 0; mtd < 4; mtd++)
        vc[mtd] = *(const bf16x8*)(Vtb + (long)(mtd * 16 + l16) * vtstr + kbase + l4 * 8);

      // S^T tiles: A = K rows (m=key), B = Q rows (n=q)
      floatx4 sacc[2][4];
#pragma unroll
      for (int mt = 0; mt < 2; mt++)
#pragma unroll
        for (int qtt = 0; qtt < 4; qtt++) sacc[mt][qtt] = (floatx4){0.f, 0.f, 0.f, 0.f};
#pragma unroll
      for (int ds = 0; ds < 2; ds++)
#pragma unroll
        for (int mt = 0; mt < 2; mt++)
#pragma unroll
          for (int qtt = 0; qtt < 4; qtt++)
            sacc[mt][qtt] = __builtin_amdgcn_mfma_f32_16x16x32_bf16(kc[mt][ds], qf[qtt][ds], sacc[mt][qtt], 0, 0, 0);

      if (kt + 1 < nkt) {  // prefetch next K
        const int nb = kbase + 128;
#pragma unroll
        for (int mt = 0; mt < 2; mt++)
#pragma unroll
          for (int ds = 0; ds < 2; ds++)
            kn[mt][ds] = *(const bf16x8*)(Kb + (long)(nb + mt * 16 + l16) * kstr + ds * 32 + l4 * 8);
      }

      // causal mask (finite NEG; only last self tile straddles)
      if (phase == 0 && kt == nkt - 1) {
#pragma unroll
        for (int mt = 0; mt < 2; mt++) {
          int keyb = kbase + mt * 16 + l4 * 4;
#pragma unroll
          for (int qtt = 0; qtt < 4; qtt++) {
            int q = q0 + qtt * 16 + l16;
#pragma unroll
            for (int r = 0; r < 4; r++)
              if (keyb + r > q) sacc[mt][qtt][r] = NEG;
          }
        }
      }

      // per-wave online softmax (reduce across l4 groups only: xor 16, 32)
      float alpha[4];
      uint2 pd[4][2];
      int changed = 0;
#pragma unroll
      for (int qtt = 0; qtt < 4; qtt++) {
        float mx = fmaxf(fmaxf(fmaxf(sacc[0][qtt][0], sacc[0][qtt][1]), fmaxf(sacc[0][qtt][2], sacc[0][qtt][3])),
                         fmaxf(fmaxf(sacc[1][qtt][0], sacc[1][qtt][1]), fmaxf(sacc[1][qtt][2], sacc[1][qtt][3])));
        mx = fmaxf(mx, __shfl_xor(mx, 16));
        mx = fmaxf(mx, __shfl_xor(mx, 32));
        mx = fmaxf(mx, m_i[qtt]);
        alpha[qtt] = EXP2(m_i[qtt] - mx);
        changed |= (mx > m_i[qtt]) ? 1 : 0;
        m_i[qtt] = mx;
        float rs = 0.f;
#pragma unroll
        for (int mt = 0; mt < 2; mt++) {
          float p0 = EXP2(sacc[mt][qtt][0] - mx), p1 = EXP2(sacc[mt][qtt][1] - mx);
          float p2 = EXP2(sacc[mt][qtt][2] - mx), p3 = EXP2(sacc[mt][qtt][3] - mx);
          rs += (p0 + p1) + (p2 + p3);
          pd[qtt][mt].x = pack_bf16(p0, p1);
          pd[qtt][mt].y = pack_bf16(p2, p3);
        }
        rs += __shfl_xor(rs, 16);
        rs += __shfl_xor(rs, 32);
        l_i[qtt] = l_i[qtt] * alpha[qtt] + rs;
      }
      if (__any(changed)) {
#pragma unroll
        for (int mtd = 0; mtd < 4; mtd++)
#pragma unroll
          for (int qtt = 0; qtt < 4; qtt++)
#pragma unroll
            for (int r = 0; r < 4; r++) oacc[mtd][qtt][r] *= alpha[qtt];
      }

      // P^T round-trip through wave-private slab (stride 44 = conflict-free)
#pragma unroll
      for (int qtt = 0; qtt < 4; qtt++)
#pragma unroll
        for (int mt = 0; mt < 2; mt++)
          *(uint2*)&Pw[(qtt * 16 + l16) * 44 + mt * 16 + l4 * 4] = pd[qtt][mt];
#pragma unroll
      for (int qtt = 0; qtt < 4; qtt++) {
        bf16x8 pf = *(const bf16x8*)&Pw[(qtt * 16 + l16) * 44 + l4 * 8];
#pragma unroll
        for (int mtd = 0; mtd < 4; mtd++)
          oacc[mtd][qtt] = __builtin_amdgcn_mfma_f32_16x16x32_bf16(vc[mtd], pf, oacc[mtd][qtt], 0, 0, 0);
      }
#pragma unroll
      for (int mt = 0; mt < 2; mt++)
#pragma unroll
        for (int ds = 0; ds < 2; ds++) kc[mt][ds] = kn[mt][ds];
    }  // kt

    // ---- flash-combine across the 4 waves ----
    if (l4 == 0) {
#pragma unroll
      for (int qtt = 0; qtt < 4; qtt++) Mbuf[w][qtt][l16] = make_float2(m_i[qtt], l_i[qtt]);
    }
    __syncthreads();
    float myscale[4], denom[4];
#pragma unroll
    for (int qtt = 0; qtt < 4; qtt++) {
      float2 s0 = Mbuf[0][qtt][l16], s1 = Mbuf[1][qtt][l16];
      float2 s2 = Mbuf[2][qtt][l16], s3 = Mbuf[3][qtt][l16];
      float M = fmaxf(fmaxf(s0.x, s1.x), fmaxf(s2.x, s3.x));
      denom[qtt] = EXP2(s0.x - M) * s0.y + EXP2(s1.x - M) * s1.y +
                   EXP2(s2.x - M) * s2.y + EXP2(s3.x - M) * s3.y;
      myscale[qtt] = EXP2(m_i[qtt] - M);
    }
    // scaled O^T partials (bf16) -> Obuf[w][q][d]
#pragma unroll
    for (int qtt = 0; qtt < 4; qtt++)
#pragma unroll
      for (int mtd = 0; mtd < 4; mtd++) {
        float s = myscale[qtt];
        uint2 u = {pack_bf16(oacc[mtd][qtt][0] * s, oacc[mtd][qtt][1] * s),
                   pack_bf16(oacc[mtd][qtt][2] * s, oacc[mtd][qtt][3] * s)};
        *(uint2*)&U[((w * 64) + qtt * 16 + l16) * 72 + mtd * 16 + l4 * 4] = u;
      }
    __syncthreads();
    // owner: q = q0 + w*16 + l16, d = l4*16 .. +16
    float sum[16];
#pragma unroll
    for (int j = 0; j < 16; j++) sum[j] = 0.f;
#pragma unroll
    for (int s = 0; s < 4; s++) {
      bf16x8 c0 = *(const bf16x8*)&U[((s * 64) + w * 16 + l16) * 72 + l4 * 16];
      bf16x8 c1 = *(const bf16x8*)&U[((s * 64) + w * 16 + l16) * 72 + l4 * 16 + 8];
#pragma unroll
      for (int j = 0; j < 8; j++) { sum[j] += (float)c0[j]; sum[8 + j] += (float)c1[j]; }
    }
    float invd = 1.0f / denom[w];
    if (phase == 0) {
#pragma unroll
      for (int j = 0; j < 16; j++) o_self[j] = sum[j] * invd;
    } else {
      long row = (long)b * 2048 + q0 + w * 16 + l16;
      bf16 out[16];
#pragma unroll
      for (int j = 0; j < 16; j++) out[j] = (bf16)(o_self[j] + sum[j] * invd);
      *(bf16x8*)&Y[row * 1024 + h * 64 + l4 * 16] = *(const bf16x8*)&out[0];
      *(bf16x8*)&Y[row * 1024 + h * 64 + l4 * 16 + 8] = *(const bf16x8*)&out[8];
    }
  }  // phase
}

extern "C" void kernel_launch(void* const* d_in, const int* in_sizes, int n_in,
                              void* d_out, int out_size, void* d_ws, size_t ws_size,
                              hipStream_t stream) {
  const float* x   = (const float*)d_in[0];
  const float* xc  = (const float*)d_in[1];
  const float* Wk  = (const float*)d_in[2];  const float* bk  = (const float*)d_in[3];
  const float* Wq  = (const float*)d_in[4];  const float* bq  = (const float*)d_in[5];
  const float* Wv  = (const float*)d_in[6];  const float* bv  = (const float*)d_in[7];
  const float* Wck = (const float*)d_in[8];  const float* bck = (const float*)d_in[9];
  const float* Wcq = (const float*)d_in[10]; const float* bcq = (const float*)d_in[11];
  const float* Wcv = (const float*)d_in[12]; const float* bcv = (const float*)d_in[13];
  const float* Wp  = (const float*)d_in[14]; const float* bp  = (const float*)d_in[15];

  char* ws = (char*)d_ws;
  const size_t MB = 1ull << 20;
  bf16*  WT_all = (bf16*)(ws + 0);         // [4096][1024]: Q|K|V|Qc
  bf16*  WC_all = (bf16*)(ws + 8 * MB);    // [2048][512]: Kc|Vc
  bf16*  WpT    = (bf16*)(ws + 10 * MB);   // [1024][1024]
  bf16*  xbf    = (bf16*)(ws + 12 * MB);   // [4096][1024]; Yb overlays after projections
  bf16*  Yb     = xbf;
  bf16*  xcbf   = (bf16*)(ws + 20 * MB);   // [1024][512]
  float* bias4  = (float*)(ws + 21 * MB);          // [4096]: bq|bk|bv|bcq
  float* biasc  = (float*)(ws + 21 * MB + 65536);  // [2048]: bck|bcv
  bf16*  QKQc   = (bf16*)(ws + 22 * MB);   // [4096][3072]: Q|K|Qc (compacted)
  bf16*  VtB    = (bf16*)(ws + 46 * MB);   // [2][16][64][2048]
  bf16*  KcB    = (bf16*)(ws + 54 * MB);   // [1024][1024]
  bf16*  VctB   = (bf16*)(ws + 56 * MB);   // [2][16][64][512]

  PrepArgs pa;
  pa.x = x; pa.xc = xc; pa.xbf = xbf; pa.xcbf = xcbf;
  pa.b4[0] = bq; pa.b4[1] = bk; pa.b4[2] = bv; pa.b4[3] = bcq;
  pa.bc[0] = bck; pa.bc[1] = bcv;
  pa.bias4 = bias4; pa.biasc = biasc;
  pa.W[0] = Wq;  pa.WT[0] = WT_all + 0ll * 1024 * 1024;
  pa.W[1] = Wk;  pa.WT[1] = WT_all + 1ll * 1024 * 1024;
  pa.W[2] = Wv;  pa.WT[2] = WT_all + 2ll * 1024 * 1024;
  pa.W[3] = Wcq; pa.WT[3] = WT_all + 3ll * 1024 * 1024;
  pa.W[4] = Wp;  pa.WT[4] = WpT;
  pa.W[5] = Wck; pa.WT[5] = WC_all + 0ll * 1024 * 512;
  pa.W[6] = Wcv; pa.WT[6] = WC_all + 1ll * 1024 * 512;
  prep_kernel<<<10776, 256, 0, stream>>>(pa);

  // fused QKV+Qc projection: N=4096; V section [2048,3072) -> VtB transposed;
  // Q/Qc columns pre-scaled by 0.125*log2e for exp2-softmax
  gemm128<bf16><<<dim3(32, 32), 256, 0, stream>>>(xbf, WT_all, bias4, QKQc,
                                                  4096, 4096, 1024, 3072,
                                                  VtB, 2048, 3072, 2048, 11, 1);
  // fused cross K+V: N=2048; Vc section [1024,2048) -> VctB transposed
  gemm128<bf16><<<dim3(16, 8), 256, 0, stream>>>(xcbf, WC_all, biasc, KcB,
                                                 1024, 2048, 512, 1024,
                                                 VctB, 1024, 2048, 512, 9, 0);

  attn_kernel<<<dim3(32, 32), 256, 0, stream>>>(QKQc, VtB, KcB, VctB, Yb);

  gemm128<float><<<dim3(8, 32), 256, 0, stream>>>(Yb, WpT, bp, (float*)d_out,
                                                  4096, 1024, 1024, 1024,
                                                  nullptr, -1, -1, 0, 0, 0);
}